// Round 7
// baseline (15.455 us; speedup 1.0000x reference)
//
#include <hip/hip_runtime.h>

// LogLinearModel: logits[b,j,v] = bias[v] + sum_{p=0..3} W[v, x[b,j-4+p]*4 + p]  (j>=4)
//                 logits[b,j,v] = bias[v]                                        (j<4)
// B=32, L=4096, N_SYM=64, D=256. Output fp32 (B,L,64) = 32MB -> store-BW-bound.
//
// R7: phase-split main loop. Compute all 16 accumulators into distinct regs,
// THEN issue all 16 stores back-to-back (no acc-register reuse -> no mid-loop
// s_waitcnt vmcnt, 16KB in-flight stores per wave, 128KB/CU >> Little's law
// ~15KB needed for 6.3 TB/s). Table and staging identical to R6 (fp32, exact).

#define NSYM   64
#define CTX    4
#define DFEAT  256
#define LSEQ   4096
#define NPOS   (32 * LSEQ)          // 131072 positions
#define POS_PER_BLOCK 256
#define BLOCKS (NPOS / POS_PER_BLOCK)   // 512

typedef float vfloat4 __attribute__((ext_vector_type(4)));

__global__ __launch_bounds__(256, 2)
void loglinear_kernel(const int* __restrict__ x,
                      const float* __restrict__ W,
                      const float* __restrict__ bias,
                      float* __restrict__ out) {
    __shared__ float    wt[DFEAT * NSYM];     // 64 KB: wt[c*64 + v] = W[v][c]
    __shared__ unsigned xw[POS_PER_BLOCK];    // packed 4-symbol context windows

    const int t  = threadIdx.x;
    const int PB = blockIdx.x * POS_PER_BLOCK;
    const int jb = PB & (LSEQ - 1);   // j at block start (blocks never straddle batches)

    // ---- xw[k]: symbols at positions PB+k-4 .. PB+k-1, one byte each ----
    {
        unsigned w = 0;
        #pragma unroll
        for (int p = 0; p < CTX; ++p) {
            const int idx = PB - CTX + t + p;
            const int sym = (idx >= 0) ? x[idx] : 0;
            w |= (unsigned)sym << (8 * p);
        }
        xw[t] = w;
    }

    // ---- wt[c][v] = W[v][c], fp32 transpose ----
    {
        const int v = t & 63;
        const int chunk = t >> 6;
        #pragma unroll
        for (int it = 0; it < 16; ++it) {
            const int d0 = (chunk * 16 + it) * 4;
            const float4 wv = *reinterpret_cast<const float4*>(W + v * DFEAT + d0);
            wt[(d0    ) * 64 + v] = wv.x;
            wt[(d0 + 1) * 64 + v] = wv.y;
            wt[(d0 + 2) * 64 + v] = wv.z;
            wt[(d0 + 3) * 64 + v] = wv.w;
        }
    }
    __syncthreads();

    const int lane = t & 63;
    const int wave = t >> 6;
    const int g = lane >> 4;      // position sub-index (0..3)
    const int q = lane & 15;      // v-quad (float4 of outputs)
    const int jbase = wave * 64;  // wave's first position within block

    const float4 bq = reinterpret_cast<const float4*>(bias)[q];
    const vfloat4 b4 = {bq.x, bq.y, bq.z, bq.w};

    // lane handles positions jbase + g + 4m, m = 0..15
    // ---- phase 0: prefetch all 16 packed windows (broadcast b32 reads) ----
    unsigned wreg[16];
    #pragma unroll
    for (int m = 0; m < 16; ++m) wreg[m] = xw[jbase + g + 4 * m];

    // ---- phase 1: compute all 16 accumulators (distinct registers) ----
    const bool bias0 = (jb == 0) && (wave == 0);   // m==0 covers j = g < 4
    vfloat4 acc[16];
    #pragma unroll
    for (int m = 0; m < 16; ++m) acc[m] = b4;
    #pragma unroll
    for (int m = 0; m < 16; ++m) {
        if (!(m == 0 && bias0)) {
            #pragma unroll
            for (int p = 0; p < CTX; ++p) {
                const int sym = (wreg[m] >> (8 * p)) & 0xff;
                acc[m] += *reinterpret_cast<const vfloat4*>(
                    wt + sym * 256 + p * 64 + q * 4);   // b128, min-bank-pass
            }
        }
    }

    // ---- phase 2: 16 back-to-back dwordx4 stores, no register reuse ----
    vfloat4* __restrict__ outp =
        reinterpret_cast<vfloat4*>(out) + (size_t)(PB + jbase + g) * 16 + q;
    #pragma unroll
    for (int m = 0; m < 16; ++m) outp[m * 64] = acc[m];   // 1KB/instr coalesced
}

extern "C" void kernel_launch(void* const* d_in, const int* in_sizes, int n_in,
                              void* d_out, int out_size, void* d_ws, size_t ws_size,
                              hipStream_t stream) {
    const int*   x   = (const int*)d_in[0];
    const float* W   = (const float*)d_in[1];
    const float* b   = (const float*)d_in[2];
    float*       out = (float*)d_out;

    hipLaunchKernelGGL(loglinear_kernel, dim3(BLOCKS), dim3(256), 0, stream,
                       x, W, b, out);
}